// Round 1
// 745.300 us; speedup vs baseline: 1.1686x; 1.1686x over previous
//
#include <hip/hip_runtime.h>
#include <hip/hip_bf16.h>

typedef unsigned short u16;
typedef unsigned int u32;
typedef __attribute__((ext_vector_type(8))) short bf16x8;   // 8 bf16 in 4 VGPRs
typedef __attribute__((ext_vector_type(4))) short bf16x4;   // 4 bf16 in 2 VGPRs
typedef __attribute__((ext_vector_type(4))) float f32x4;

#define T_TOKENS 50176   // 2*128*196
#define D_MODEL  1024
#define D_INNER  2048
#define D_STATE  8

__device__ __forceinline__ u16 f2bf(float f) {
    u32 u = __builtin_bit_cast(u32, f);
    u += 0x7fffu + ((u >> 16) & 1u);   // RNE
    return (u16)(u >> 16);
}
__device__ __forceinline__ float bf2f(u16 h) {
    u32 u = ((u32)h) << 16;
    return __builtin_bit_cast(float, u);
}
__device__ __forceinline__ float silu(float v) {
    return v / (1.f + __expf(-v));
}

// K=16 bf16 MFMA for the fused state-projection epilogue.
__device__ __forceinline__ f32x4 mfma_16x16x16_bf16(bf16x4 a, bf16x4 b, f32x4 c) {
#if __has_builtin(__builtin_amdgcn_mfma_f32_16x16x16bf16_1k)
    return __builtin_amdgcn_mfma_f32_16x16x16bf16_1k(a, b, c, 0, 0, 0);
#else
    f32x4 d;
    asm("v_mfma_f32_16x16x16_bf16 %0, %1, %2, %3" : "=v"(d) : "v"(a), "v"(b), "v"(c));
    return d;
#endif
}

// ---------------------------------------------------------------- K1: LayerNorm -> bf16 (into d_out)
__global__ __launch_bounds__(256) void k_ln(const float* __restrict__ x,
                                            const float* __restrict__ gamma,
                                            const float* __restrict__ beta,
                                            u16* __restrict__ xn) {
    const int w = threadIdx.x >> 6, lane = threadIdx.x & 63;
    const int tok = blockIdx.x * 4 + w;                 // 12544 blocks * 4 waves = 50176
    const float* xr = x + (size_t)tok * D_MODEL;
    float4 v[4];
    float s1 = 0.f, s2 = 0.f;
#pragma unroll
    for (int c = 0; c < 4; ++c) {
        v[c] = *(const float4*)(xr + c * 256 + lane * 4);
        s1 += v[c].x + v[c].y + v[c].z + v[c].w;
        s2 += v[c].x * v[c].x + v[c].y * v[c].y + v[c].z * v[c].z + v[c].w * v[c].w;
    }
#pragma unroll
    for (int off = 32; off; off >>= 1) {
        s1 += __shfl_xor(s1, off, 64);
        s2 += __shfl_xor(s2, off, 64);
    }
    const float mu = s1 * (1.f / 1024.f);
    const float var = s2 * (1.f / 1024.f) - mu * mu;
    const float rstd = rsqrtf(var + 1e-5f);
    u16* orow = xn + (size_t)tok * D_MODEL;
#pragma unroll
    for (int c = 0; c < 4; ++c) {
        const int d = c * 256 + lane * 4;
        float4 g = *(const float4*)(gamma + d);
        float4 b = *(const float4*)(beta + d);
        ushort4 o;
        o.x = f2bf((v[c].x - mu) * rstd * g.x + b.x);
        o.y = f2bf((v[c].y - mu) * rstd * g.y + b.y);
        o.z = f2bf((v[c].z - mu) * rstd * g.z + b.z);
        o.w = f2bf((v[c].w - mu) * rstd * g.w + b.w);
        *(ushort4*)(orow + d) = o;
    }
}

// ---------------------------------------------------------------- K1b: W_proj fp32 -> bf16
__global__ __launch_bounds__(256) void k_cvt(const float* __restrict__ W, u16* __restrict__ Wb) {
    const int i = (blockIdx.x * 256 + threadIdx.x) * 4;   // 2048 blocks covers 2048*1024
    float4 v = *(const float4*)(W + i);
    ushort4 o = {f2bf(v.x), f2bf(v.y), f2bf(v.z), f2bf(v.w)};
    *(ushort4*)(Wb + i) = o;
}

// ---------------------------------------------------------------- K2: bf16 GEMM + MFMA-fused silu*W_state^T partial reduce
// A [T,1024] bf16, B=W_proj [2048,1024] bf16.  Tile 128x128, BK=64, 4 waves (2x2 of 64x64).
// MAIN MFMA HAS SWAPPED OPERANDS: acc[ci][ti] holds C^T, i.e. lane layout
// (inner col = q*4+r in regs, token row = c15 in lanes).  That is exactly the
// A-frag / B-frag layout of v_mfma_f32_16x16x16_bf16, so the state projection
// (sum over inner cols of silu(C)*W_state) is done with 16 K=16 MFMAs per wave
// instead of 512 scalar FMAs + 512 __shfl_xor per thread.
// Output: partials[T][32][8] fp32, slot index = bn*2 + (wave&1).
__global__ __launch_bounds__(256) void k_gemm(const u16* __restrict__ A,
                                              const u16* __restrict__ B,
                                              const float* __restrict__ bproj,
                                              const float* __restrict__ Wstate,   // [8][2048] fp32
                                              float* __restrict__ part) {
    __shared__ u16 As[128 * 64];
    __shared__ u16 Bs[128 * 64];
    const int t = threadIdx.x;
    const int w = t >> 6, lane = t & 63;
    const int q = lane >> 4, c15 = lane & 15;
    const int bn = blockIdx.x, bm = blockIdx.y;
    const int wm = (w >> 1) * 64, wn = (w & 1) * 64;

    f32x4 acc[4][4];   // [ci = inner tile][ti = token tile]
#pragma unroll
    for (int ci = 0; ci < 4; ++ci)
#pragma unroll
        for (int ti = 0; ti < 4; ++ti) acc[ci][ti] = (f32x4){0.f, 0.f, 0.f, 0.f};

    // staging coords: 256 thr * 16B = 32 rows/issue; XOR swizzle chunk^=(row&7)
    const int srow = t >> 3;
    const int sch = (t & 7) ^ (srow & 7);
    const u16* Ag = A + (size_t)(bm * 128 + srow) * 1024 + sch * 8;
    const u16* Bg = B + (size_t)(bn * 128 + srow) * 1024 + sch * 8;
    u16* lA = &As[t * 8];
    u16* lB = &Bs[t * 8];

    for (int kb = 0; kb < 16; ++kb) {
        __syncthreads();
#pragma unroll
        for (int i = 0; i < 4; ++i) {
            __builtin_amdgcn_global_load_lds(
                (const __attribute__((address_space(1))) void*)(Ag + (size_t)i * 32 * 1024 + kb * 64),
                (__attribute__((address_space(3))) void*)(lA + i * 2048), 16, 0, 0);
            __builtin_amdgcn_global_load_lds(
                (const __attribute__((address_space(1))) void*)(Bg + (size_t)i * 32 * 1024 + kb * 64),
                (__attribute__((address_space(3))) void*)(lB + i * 2048), 16, 0, 0);
        }
        __syncthreads();
#pragma unroll
        for (int ks = 0; ks < 2; ++ks) {
            bf16x8 xf[4], wf[4];
            const int chb = (ks * 4 + q) ^ (c15 & 7);
#pragma unroll
            for (int ti = 0; ti < 4; ++ti)
                xf[ti] = *(const bf16x8*)&As[(wm + ti * 16 + c15) * 64 + chb * 8];
#pragma unroll
            for (int ci = 0; ci < 4; ++ci)
                wf[ci] = *(const bf16x8*)&Bs[(wn + ci * 16 + c15) * 64 + chb * 8];
#pragma unroll
            for (int ci = 0; ci < 4; ++ci)
#pragma unroll
                for (int ti = 0; ti < 4; ++ti)
                    // swapped operands: D = Wproj_frag * xn_frag -> C^T layout
                    acc[ci][ti] = __builtin_amdgcn_mfma_f32_16x16x32_bf16(wf[ci], xf[ti], acc[ci][ti], 0, 0, 0);
        }
    }

    // ---- fused epilogue v2: sv = silu(acc + b_proj) (bf16), partials via 16x16x16 MFMA.
    // Lane (q,c15) holds acc value r at (inner = bn*128+wn+ci*16+q*4+r, token = bm*128+wm+ti*16+c15).
    const int ib0 = bn * 128 + wn + q * 4;
    f32x4 bp4[4];
    bf16x4 wsf[4];
#pragma unroll
    for (int ci = 0; ci < 4; ++ci) {
        const int ib = ib0 + ci * 16;
        bp4[ci] = *(const f32x4*)(bproj + ib);
        if (c15 < 8) {
            f32x4 wv = *(const f32x4*)(Wstate + (size_t)c15 * D_INNER + ib);
            wsf[ci] = (bf16x4){(short)f2bf(wv[0]), (short)f2bf(wv[1]), (short)f2bf(wv[2]), (short)f2bf(wv[3])};
        } else {
            wsf[ci] = (bf16x4){0, 0, 0, 0};   // A-frag rows 8..15 = 0 -> D rows 8..15 = 0 (unused)
        }
    }
    const int slot = bn * 2 + (w & 1);
#pragma unroll
    for (int ti = 0; ti < 4; ++ti) {
        f32x4 a2 = (f32x4){0.f, 0.f, 0.f, 0.f};
#pragma unroll
        for (int ci = 0; ci < 4; ++ci) {
            bf16x4 sv;
#pragma unroll
            for (int r = 0; r < 4; ++r) {
                const float s = silu(acc[ci][ti][r] + bp4[ci][r]);
                sv[r] = (short)f2bf(s);
            }
            // A = W_state[state=c15][k=q*4+r], B = sv[k=inner][n=token row=c15]
            // D[m=state in q*4+r regs][n=token row in c15 lanes]
            a2 = mfma_16x16x16_bf16(wsf[ci], sv, a2);
        }
        if (q < 2) {   // q=0: states 0..3, q=1: states 4..7 -> one contiguous 16B store
            const int row = bm * 128 + wm + ti * 16 + c15;
            *(f32x4*)(part + (size_t)row * 256 + slot * 8 + q * 4) = a2;
        }
    }
}

// ---------------------------------------------------------------- K3: sum partials, silu, xW_out^T, +x
__global__ __launch_bounds__(256) void k_out2(const float* __restrict__ x,
                                              const float* __restrict__ part,   // [T][32][8]
                                              const float* __restrict__ Wout,   // [1024][8]
                                              const float* __restrict__ bout,   // [1024]
                                              const float* __restrict__ bstate, // [8]
                                              const float* __restrict__ s0,     // [8]
                                              float* __restrict__ out) {
    // W_out in LDS as 16B slots, swizzled: slot(d,h) = (d*2+h) ^ ((d>>2)&7)
    __shared__ float4 wol[2048];   // 32 KB
    const int t = threadIdx.x;
    const float4* Wg4 = (const float4*)Wout;
#pragma unroll
    for (int i = 0; i < 8; ++i) {
        const int g = i * 256 + t;
        const int d = g >> 1;
        wol[g ^ ((d >> 2) & 7)] = Wg4[g];
    }
    __syncthreads();

    const int w = t >> 6, lane = t & 63;
    const int tok = blockIdx.x * 4 + w;

    // partials: 256 f32 per token = 64 float4, one per lane; butterfly-reduce (parity-preserving)
    const float4* p4 = (const float4*)(part + (size_t)tok * 256);
    float4 pv = p4[lane];
    float pa[4] = {pv.x, pv.y, pv.z, pv.w};
#pragma unroll
    for (int off = 2; off < 64; off <<= 1)
#pragma unroll
        for (int j = 0; j < 4; ++j) pa[j] += __shfl_xor(pa[j], off, 64);
    float cs[8];
#pragma unroll
    for (int j = 0; j < 4; ++j) {
        const float sl = __shfl(pa[j], 0, 64);          // states 0..3 on even lanes
        const float sh = __shfl(pa[j], 1, 64);          // states 4..7 on odd lanes
        cs[j]     = silu(sl + s0[j]     + bstate[j]);
        cs[4 + j] = silu(sh + s0[4 + j] + bstate[4 + j]);
    }

    const float* xr = x + (size_t)tok * D_MODEL;
    float* orow = out + (size_t)tok * D_MODEL;
#pragma unroll
    for (int c = 0; c < 16; ++c) {
        const int d = c * 64 + lane;
        const int m = (d >> 2) & 7;
        const float4 w0 = wol[(d * 2) ^ m];
        const float4 w1 = wol[(d * 2 + 1) ^ m];
        float a = xr[d] + bout[d];
        a += cs[0] * w0.x + cs[1] * w0.y + cs[2] * w0.z + cs[3] * w0.w;
        a += cs[4] * w1.x + cs[5] * w1.y + cs[6] * w1.z + cs[7] * w1.w;
        orow[d] = a;
    }
}

extern "C" void kernel_launch(void* const* d_in, const int* in_sizes, int n_in,
                              void* d_out, int out_size, void* d_ws, size_t ws_size,
                              hipStream_t stream) {
    const float* x      = (const float*)d_in[0];
    const float* Wproj  = (const float*)d_in[1];
    const float* bproj  = (const float*)d_in[2];
    const float* Wstate = (const float*)d_in[3];
    const float* bstate = (const float*)d_in[4];
    const float* Wout   = (const float*)d_in[5];
    const float* bout   = (const float*)d_in[6];
    const float* s0     = (const float*)d_in[7];
    const float* gamma  = (const float*)d_in[8];
    const float* beta   = (const float*)d_in[9];

    u16* xn = (u16*)d_out;                               // LN output (bf16) borrows d_out;
                                                         // fully consumed by k_gemm before k_out2 overwrites
    u16* Wb = (u16*)d_ws;                                // 4 MB
    float* partials = (float*)((char*)d_ws + (size_t)D_INNER * D_MODEL * sizeof(u16));  // 51.4 MB
    float* out = (float*)d_out;

    k_ln  <<<T_TOKENS / 4, 256, 0, stream>>>(x, gamma, beta, xn);
    k_cvt <<<(D_INNER * D_MODEL) / 1024, 256, 0, stream>>>(Wproj, Wb);
    k_gemm<<<dim3(D_INNER / 128, T_TOKENS / 128), 256, 0, stream>>>(xn, Wb, bproj, Wstate, partials);
    k_out2<<<T_TOKENS / 4, 256, 0, stream>>>(x, partials, Wout, bout, bstate, s0, out);
}

// Round 2
// 692.569 us; speedup vs baseline: 1.2576x; 1.0761x over previous
//
#include <hip/hip_runtime.h>
#include <hip/hip_bf16.h>

typedef unsigned short u16;
typedef unsigned int u32;
typedef __attribute__((ext_vector_type(8))) short bf16x8;   // 8 bf16 in 4 VGPRs
typedef __attribute__((ext_vector_type(4))) short bf16x4;   // 4 bf16 in 2 VGPRs
typedef __attribute__((ext_vector_type(4))) float f32x4;

#define T_TOKENS 50176   // 2*128*196
#define D_MODEL  1024
#define D_INNER  2048
#define D_STATE  8

__device__ __forceinline__ u16 f2bf(float f) {
    u32 u = __builtin_bit_cast(u32, f);
    u += 0x7fffu + ((u >> 16) & 1u);   // RNE
    return (u16)(u >> 16);
}
__device__ __forceinline__ float silu(float v) {
    return v / (1.f + __expf(-v));
}

// K=16 bf16 MFMA for the fused state-projection epilogue.
__device__ __forceinline__ f32x4 mfma_16x16x16_bf16(bf16x4 a, bf16x4 b, f32x4 c) {
#if __has_builtin(__builtin_amdgcn_mfma_f32_16x16x16bf16_1k)
    return __builtin_amdgcn_mfma_f32_16x16x16bf16_1k(a, b, c, 0, 0, 0);
#else
    f32x4 d;
    asm("v_mfma_f32_16x16x16_bf16 %0, %1, %2, %3" : "=v"(d) : "v"(a), "v"(b), "v"(c));
    return d;
#endif
}

// ---------------------------------------------------------------- K1: LayerNorm -> bf16 (into d_out)
__global__ __launch_bounds__(256) void k_ln(const float* __restrict__ x,
                                            const float* __restrict__ gamma,
                                            const float* __restrict__ beta,
                                            u16* __restrict__ xn) {
    const int w = threadIdx.x >> 6, lane = threadIdx.x & 63;
    const int tok = blockIdx.x * 4 + w;                 // 12544 blocks * 4 waves = 50176
    const float* xr = x + (size_t)tok * D_MODEL;
    float4 v[4];
    float s1 = 0.f, s2 = 0.f;
#pragma unroll
    for (int c = 0; c < 4; ++c) {
        v[c] = *(const float4*)(xr + c * 256 + lane * 4);
        s1 += v[c].x + v[c].y + v[c].z + v[c].w;
        s2 += v[c].x * v[c].x + v[c].y * v[c].y + v[c].z * v[c].z + v[c].w * v[c].w;
    }
#pragma unroll
    for (int off = 32; off; off >>= 1) {
        s1 += __shfl_xor(s1, off, 64);
        s2 += __shfl_xor(s2, off, 64);
    }
    const float mu = s1 * (1.f / 1024.f);
    const float var = s2 * (1.f / 1024.f) - mu * mu;
    const float rstd = rsqrtf(var + 1e-5f);
    u16* orow = xn + (size_t)tok * D_MODEL;
#pragma unroll
    for (int c = 0; c < 4; ++c) {
        const int d = c * 256 + lane * 4;
        float4 g = *(const float4*)(gamma + d);
        float4 b = *(const float4*)(beta + d);
        ushort4 o;
        o.x = f2bf((v[c].x - mu) * rstd * g.x + b.x);
        o.y = f2bf((v[c].y - mu) * rstd * g.y + b.y);
        o.z = f2bf((v[c].z - mu) * rstd * g.z + b.z);
        o.w = f2bf((v[c].w - mu) * rstd * g.w + b.w);
        *(ushort4*)(orow + d) = o;
    }
}

// ---------------------------------------------------------------- K1b: W_proj fp32 -> bf16
__global__ __launch_bounds__(256) void k_cvt(const float* __restrict__ W, u16* __restrict__ Wb) {
    const int i = (blockIdx.x * 256 + threadIdx.x) * 4;   // 2048 blocks covers 2048*1024
    float4 v = *(const float4*)(W + i);
    ushort4 o = {f2bf(v.x), f2bf(v.y), f2bf(v.z), f2bf(v.w)};
    *(ushort4*)(Wb + i) = o;
}

// ---------------------------------------------------------------- K2: 256x256 8-wave 4-phase bf16 GEMM
// A [T,1024] bf16 (tokens), B=W_proj [2048,1024] bf16.  BM=BN=256, BK=64, 8 waves (2M x 4N),
// per-wave output 128(tok) x 64(inner).  Double-buffered 128 KiB LDS, counted vmcnt (never 0
// in main loop), raw s_barrier pairs per phase, setprio(1) around each 16-MFMA cluster.
// Swapped MFMA operands (wf as A) -> acc holds C^T: lane (q,c15) reg r = (inner=q*4+r, token=c15).
// Fused epilogue: silu + W_state^T projection via 16x16x16 MFMA -> partials[T][32][8],
// slot = bn*4 + (w&3).
#define STAGE_A(i, kb, buf) \
    __builtin_amdgcn_global_load_lds( \
        (const __attribute__((address_space(1))) void*)(Ag + (i) * 65536 + (kb) * 64), \
        (__attribute__((address_space(3))) void*)(lA + (buf) * 32768 + (i) * 4096), 16, 0, 0)
#define STAGE_B(i, kb, buf) \
    __builtin_amdgcn_global_load_lds( \
        (const __attribute__((address_space(1))) void*)(Bg + (i) * 65536 + (kb) * 64), \
        (__attribute__((address_space(3))) void*)(lB + (buf) * 32768 + (i) * 4096), 16, 0, 0)
#define FENCE() asm volatile("" ::: "memory")
#define BARRIER() do { FENCE(); __builtin_amdgcn_s_barrier(); FENCE(); } while (0)

__global__ __launch_bounds__(512, 2) void k_gemm(const u16* __restrict__ A,
                                                 const u16* __restrict__ B,
                                                 const float* __restrict__ bproj,
                                                 const float* __restrict__ Wstate,   // [8][2048] fp32
                                                 float* __restrict__ part) {
    __shared__ u16 sm[65536];   // 128 KiB: [buf0: A 32K | B 32K][buf1: A 32K | B 32K]
    const int t = threadIdx.x;
    const int w = t >> 6, lane = t & 63;
    const int q = lane >> 4, c15 = lane & 15;
    const int bn = blockIdx.x, bm = blockIdx.y;
    const int wm = (w >> 2) * 128, wn = (w & 3) * 64;

    f32x4 acc[4][8];   // [ci = inner tile 0..3][ti = token tile 0..7]
#pragma unroll
    for (int ci = 0; ci < 4; ++ci)
#pragma unroll
        for (int ti = 0; ti < 8; ++ti) acc[ci][ti] = (f32x4){0.f, 0.f, 0.f, 0.f};

    // staging coords: 512 thr * 16B = 64 rows/issue; XOR chunk swizzle (involution, rule 21)
    const int srow = t >> 3;                       // 0..63
    const int gch = (t & 7) ^ (srow & 7);
    const u16* Ag = A + (size_t)(bm * 256 + srow) * 1024 + gch * 8;
    const u16* Bg = B + (size_t)(bn * 256 + srow) * 1024 + gch * 8;
    u16* lA = &sm[t * 8];
    u16* lB = &sm[16384 + t * 8];

    // LDS fragment reads (swizzled chunk; row&7 == c15&7 since wm/wn/ti*16 are 8-multiples)
    auto LDA = [&](int buf, int ti, int ks) -> bf16x8 {
        const int row = wm + ti * 16 + c15;
        const int ch = (ks * 4 + q) ^ (c15 & 7);
        return *(const bf16x8*)&sm[buf * 32768 + row * 64 + ch * 8];
    };
    auto LDB = [&](int buf, int ci, int ks) -> bf16x8 {
        const int row = wn + ci * 16 + c15;
        const int ch = (ks * 4 + q) ^ (c15 & 7);
        return *(const bf16x8*)&sm[buf * 32768 + 16384 + row * 64 + ch * 8];
    };

    // ---- prologue: tile0 fully staged into buf0, tile1 slots{0,1} in flight into buf1
    STAGE_A(0, 0, 0); STAGE_A(1, 0, 0); STAGE_A(2, 0, 0); STAGE_A(3, 0, 0);
    STAGE_B(0, 0, 0); STAGE_B(1, 0, 0); STAGE_B(2, 0, 0); STAGE_B(3, 0, 0);
    STAGE_A(0, 1, 1); STAGE_A(1, 1, 1);
    asm volatile("s_waitcnt vmcnt(2)" ::: "memory");
    BARRIER();

#pragma unroll 2
    for (int tt = 0; tt < 16; ++tt) {
        const int cur = tt & 1, nxt = cur ^ 1;
        const int kb1 = (tt + 1) & 15, kb2 = (tt + 2) & 15;   // wrap: stages past K are harmless
        bf16x8 xf[4][2], wf[4][2];
        // ---------------- P1: tokens half0 + inner half0
#pragma unroll
        for (int ti = 0; ti < 4; ++ti)
#pragma unroll
            for (int ks = 0; ks < 2; ++ks) xf[ti][ks] = LDA(cur, ti, ks);
#pragma unroll
        for (int ci = 0; ci < 2; ++ci)
#pragma unroll
            for (int ks = 0; ks < 2; ++ks) wf[ci][ks] = LDB(cur, ci, ks);
        STAGE_A(2, kb1, nxt); STAGE_A(3, kb1, nxt);
        BARRIER();
        __builtin_amdgcn_s_setprio(1);
#pragma unroll
        for (int ci = 0; ci < 2; ++ci)
#pragma unroll
            for (int ti = 0; ti < 4; ++ti)
#pragma unroll
                for (int ks = 0; ks < 2; ++ks)
                    acc[ci][ti] = __builtin_amdgcn_mfma_f32_16x16x32_bf16(wf[ci][ks], xf[ti][ks], acc[ci][ti], 0, 0, 0);
        __builtin_amdgcn_s_setprio(0);
        BARRIER();
        // ---------------- P2: tokens half0 + inner half1
#pragma unroll
        for (int ci = 2; ci < 4; ++ci)
#pragma unroll
            for (int ks = 0; ks < 2; ++ks) wf[ci][ks] = LDB(cur, ci, ks);
        STAGE_B(0, kb1, nxt); STAGE_B(1, kb1, nxt);
        BARRIER();
        __builtin_amdgcn_s_setprio(1);
#pragma unroll
        for (int ci = 2; ci < 4; ++ci)
#pragma unroll
            for (int ti = 0; ti < 4; ++ti)
#pragma unroll
                for (int ks = 0; ks < 2; ++ks)
                    acc[ci][ti] = __builtin_amdgcn_mfma_f32_16x16x32_bf16(wf[ci][ks], xf[ti][ks], acc[ci][ti], 0, 0, 0);
        __builtin_amdgcn_s_setprio(0);
        BARRIER();
        // ---------------- P3: tokens half1 + inner half0
#pragma unroll
        for (int ti = 0; ti < 4; ++ti)
#pragma unroll
            for (int ks = 0; ks < 2; ++ks) xf[ti][ks] = LDA(cur, 4 + ti, ks);
        STAGE_B(2, kb1, nxt); STAGE_B(3, kb1, nxt);
        BARRIER();
        __builtin_amdgcn_s_setprio(1);
#pragma unroll
        for (int ci = 0; ci < 2; ++ci)
#pragma unroll
            for (int ti = 0; ti < 4; ++ti)
#pragma unroll
                for (int ks = 0; ks < 2; ++ks)
                    acc[ci][4 + ti] = __builtin_amdgcn_mfma_f32_16x16x32_bf16(wf[ci][ks], xf[ti][ks], acc[ci][4 + ti], 0, 0, 0);
        __builtin_amdgcn_s_setprio(0);
        BARRIER();
        // ---------------- P4: tokens half1 + inner half1; stage tile tt+2 A{0,1} into buf[cur]
        // (all reads of buf[cur] finished at P3's end barrier); counted vmcnt: 10 outstanding
        // -> drain 8 = all of tile tt+1, keep tile tt+2's 2 in flight.
        STAGE_A(0, kb2, cur); STAGE_A(1, kb2, cur);
        asm volatile("s_waitcnt vmcnt(2)" ::: "memory");
        BARRIER();
        __builtin_amdgcn_s_setprio(1);
#pragma unroll
        for (int ci = 2; ci < 4; ++ci)
#pragma unroll
            for (int ti = 0; ti < 4; ++ti)
#pragma unroll
                for (int ks = 0; ks < 2; ++ks)
                    acc[ci][4 + ti] = __builtin_amdgcn_mfma_f32_16x16x32_bf16(wf[ci][ks], xf[ti][ks], acc[ci][4 + ti], 0, 0, 0);
        __builtin_amdgcn_s_setprio(0);
        BARRIER();
    }

    // ---- fused epilogue: sv = silu(acc + b_proj) (bf16), partials via 16x16x16 MFMA.
    // Lane (q,c15) holds acc[ci][ti][r] at (inner = bn*256+wn+ci*16+q*4+r, token = bm*256+wm+ti*16+c15).
    const int ib0 = bn * 256 + wn + q * 4;
    f32x4 bp4[4];
    bf16x4 wsf[4];
#pragma unroll
    for (int ci = 0; ci < 4; ++ci) {
        const int ib = ib0 + ci * 16;
        bp4[ci] = *(const f32x4*)(bproj + ib);
        if (c15 < 8) {
            f32x4 wv = *(const f32x4*)(Wstate + (size_t)c15 * D_INNER + ib);
            wsf[ci] = (bf16x4){(short)f2bf(wv[0]), (short)f2bf(wv[1]), (short)f2bf(wv[2]), (short)f2bf(wv[3])};
        } else {
            wsf[ci] = (bf16x4){0, 0, 0, 0};   // A-frag rows 8..15 = 0 -> D rows 8..15 = 0 (unused)
        }
    }
    const int slot = bn * 4 + (w & 3);
#pragma unroll
    for (int ti = 0; ti < 8; ++ti) {
        f32x4 a2 = (f32x4){0.f, 0.f, 0.f, 0.f};
#pragma unroll
        for (int ci = 0; ci < 4; ++ci) {
            bf16x4 sv;
#pragma unroll
            for (int r = 0; r < 4; ++r) {
                const float s = silu(acc[ci][ti][r] + bp4[ci][r]);
                sv[r] = (short)f2bf(s);
            }
            a2 = mfma_16x16x16_bf16(wsf[ci], sv, a2);
        }
        if (q < 2) {   // q=0: states 0..3, q=1: states 4..7 -> one contiguous 16B store
            const int row = bm * 256 + wm + ti * 16 + c15;
            *(f32x4*)(part + (size_t)row * 256 + slot * 8 + q * 4) = a2;
        }
    }
}

// ---------------------------------------------------------------- K3: sum partials, silu, xW_out^T, +x
__global__ __launch_bounds__(256) void k_out2(const float* __restrict__ x,
                                              const float* __restrict__ part,   // [T][32][8]
                                              const float* __restrict__ Wout,   // [1024][8]
                                              const float* __restrict__ bout,   // [1024]
                                              const float* __restrict__ bstate, // [8]
                                              const float* __restrict__ s0,     // [8]
                                              float* __restrict__ out) {
    // W_out in LDS as 16B slots, swizzled: slot(d,h) = (d*2+h) ^ ((d>>2)&7)
    __shared__ float4 wol[2048];   // 32 KB
    const int t = threadIdx.x;
    const float4* Wg4 = (const float4*)Wout;
#pragma unroll
    for (int i = 0; i < 8; ++i) {
        const int g = i * 256 + t;
        const int d = g >> 1;
        wol[g ^ ((d >> 2) & 7)] = Wg4[g];
    }
    __syncthreads();

    const int w = t >> 6, lane = t & 63;
    const int tok = blockIdx.x * 4 + w;

    // partials: 256 f32 per token = 64 float4, one per lane; butterfly-reduce (parity-preserving)
    const float4* p4 = (const float4*)(part + (size_t)tok * 256);
    float4 pv = p4[lane];
    float pa[4] = {pv.x, pv.y, pv.z, pv.w};
#pragma unroll
    for (int off = 2; off < 64; off <<= 1)
#pragma unroll
        for (int j = 0; j < 4; ++j) pa[j] += __shfl_xor(pa[j], off, 64);
    float cs[8];
#pragma unroll
    for (int j = 0; j < 4; ++j) {
        const float sl = __shfl(pa[j], 0, 64);          // states 0..3 on even lanes
        const float sh = __shfl(pa[j], 1, 64);          // states 4..7 on odd lanes
        cs[j]     = silu(sl + s0[j]     + bstate[j]);
        cs[4 + j] = silu(sh + s0[4 + j] + bstate[4 + j]);
    }

    const float* xr = x + (size_t)tok * D_MODEL;
    float* orow = out + (size_t)tok * D_MODEL;
#pragma unroll
    for (int c = 0; c < 16; ++c) {
        const int d = c * 64 + lane;
        const int m = (d >> 2) & 7;
        const float4 w0 = wol[(d * 2) ^ m];
        const float4 w1 = wol[(d * 2 + 1) ^ m];
        float a = xr[d] + bout[d];
        a += cs[0] * w0.x + cs[1] * w0.y + cs[2] * w0.z + cs[3] * w0.w;
        a += cs[4] * w1.x + cs[5] * w1.y + cs[6] * w1.z + cs[7] * w1.w;
        orow[d] = a;
    }
}

extern "C" void kernel_launch(void* const* d_in, const int* in_sizes, int n_in,
                              void* d_out, int out_size, void* d_ws, size_t ws_size,
                              hipStream_t stream) {
    const float* x      = (const float*)d_in[0];
    const float* Wproj  = (const float*)d_in[1];
    const float* bproj  = (const float*)d_in[2];
    const float* Wstate = (const float*)d_in[3];
    const float* bstate = (const float*)d_in[4];
    const float* Wout   = (const float*)d_in[5];
    const float* bout   = (const float*)d_in[6];
    const float* s0     = (const float*)d_in[7];
    const float* gamma  = (const float*)d_in[8];
    const float* beta   = (const float*)d_in[9];

    u16* xn = (u16*)d_out;                               // LN output (bf16) borrows d_out;
                                                         // fully consumed by k_gemm before k_out2 overwrites
    u16* Wb = (u16*)d_ws;                                // 4 MB
    float* partials = (float*)((char*)d_ws + (size_t)D_INNER * D_MODEL * sizeof(u16));  // 51.4 MB
    float* out = (float*)d_out;

    k_ln  <<<T_TOKENS / 4, 256, 0, stream>>>(x, gamma, beta, xn);
    k_cvt <<<(D_INNER * D_MODEL) / 1024, 256, 0, stream>>>(Wproj, Wb);
    k_gemm<<<dim3(D_INNER / 256, T_TOKENS / 256), 512, 0, stream>>>(xn, Wb, bproj, Wstate, partials);
    k_out2<<<T_TOKENS / 4, 256, 0, stream>>>(x, partials, Wout, bout, bstate, s0, out);
}

// Round 3
// 680.110 us; speedup vs baseline: 1.2807x; 1.0183x over previous
//
#include <hip/hip_runtime.h>
#include <hip/hip_bf16.h>

typedef unsigned short u16;
typedef unsigned int u32;
typedef __attribute__((ext_vector_type(8))) short bf16x8;   // 8 bf16 in 4 VGPRs
typedef __attribute__((ext_vector_type(4))) short bf16x4;   // 4 bf16 in 2 VGPRs
typedef __attribute__((ext_vector_type(8))) u16 u16x8;      // 16B store unit
typedef __attribute__((ext_vector_type(4))) float f32x4;

#define T_TOKENS 50176   // 2*128*196
#define D_MODEL  1024
#define D_INNER  2048
#define D_STATE  8

__device__ __forceinline__ u16 f2bf(float f) {
    u32 u = __builtin_bit_cast(u32, f);
    u += 0x7fffu + ((u >> 16) & 1u);   // RNE
    return (u16)(u >> 16);
}
__device__ __forceinline__ float silu(float v) {
    return v / (1.f + __expf(-v));
}

// K=16 bf16 MFMA for the fused state-projection epilogue.
__device__ __forceinline__ f32x4 mfma_16x16x16_bf16(bf16x4 a, bf16x4 b, f32x4 c) {
#if __has_builtin(__builtin_amdgcn_mfma_f32_16x16x16bf16_1k)
    return __builtin_amdgcn_mfma_f32_16x16x16bf16_1k(a, b, c, 0, 0, 0);
#else
    f32x4 d;
    asm("v_mfma_f32_16x16x16_bf16 %0, %1, %2, %3" : "=v"(d) : "v"(a), "v"(b), "v"(c));
    return d;
#endif
}

// ---------------------------------------------------------------- K1: LayerNorm -> bf16 (into d_out)
// v2: lane owns 8 consecutive elements -> 2x float4 load + 1x 16B ushort8 store (G13).
__global__ __launch_bounds__(256) void k_ln(const float* __restrict__ x,
                                            const float* __restrict__ gamma,
                                            const float* __restrict__ beta,
                                            u16* __restrict__ xn) {
    const int w = threadIdx.x >> 6, lane = threadIdx.x & 63;
    const int tok = blockIdx.x * 4 + w;                 // 12544 blocks * 4 waves = 50176
    const float* xr = x + (size_t)tok * D_MODEL;
    float4 v[2][2];
    float s1 = 0.f, s2 = 0.f;
#pragma unroll
    for (int c = 0; c < 2; ++c) {
        const int d = c * 512 + lane * 8;
        v[c][0] = *(const float4*)(xr + d);
        v[c][1] = *(const float4*)(xr + d + 4);
#pragma unroll
        for (int p = 0; p < 2; ++p) {
            s1 += v[c][p].x + v[c][p].y + v[c][p].z + v[c][p].w;
            s2 += v[c][p].x * v[c][p].x + v[c][p].y * v[c][p].y
                + v[c][p].z * v[c][p].z + v[c][p].w * v[c][p].w;
        }
    }
#pragma unroll
    for (int off = 32; off; off >>= 1) {
        s1 += __shfl_xor(s1, off, 64);
        s2 += __shfl_xor(s2, off, 64);
    }
    const float mu = s1 * (1.f / 1024.f);
    const float var = s2 * (1.f / 1024.f) - mu * mu;
    const float rstd = rsqrtf(var + 1e-5f);
    u16* orow = xn + (size_t)tok * D_MODEL;
#pragma unroll
    for (int c = 0; c < 2; ++c) {
        const int d = c * 512 + lane * 8;
        float4 g0 = *(const float4*)(gamma + d);
        float4 g1 = *(const float4*)(gamma + d + 4);
        float4 b0 = *(const float4*)(beta + d);
        float4 b1 = *(const float4*)(beta + d + 4);
        u16x8 o;
        o[0] = f2bf((v[c][0].x - mu) * rstd * g0.x + b0.x);
        o[1] = f2bf((v[c][0].y - mu) * rstd * g0.y + b0.y);
        o[2] = f2bf((v[c][0].z - mu) * rstd * g0.z + b0.z);
        o[3] = f2bf((v[c][0].w - mu) * rstd * g0.w + b0.w);
        o[4] = f2bf((v[c][1].x - mu) * rstd * g1.x + b1.x);
        o[5] = f2bf((v[c][1].y - mu) * rstd * g1.y + b1.y);
        o[6] = f2bf((v[c][1].z - mu) * rstd * g1.z + b1.z);
        o[7] = f2bf((v[c][1].w - mu) * rstd * g1.w + b1.w);
        *(u16x8*)(orow + d) = o;
    }
}

// ---------------------------------------------------------------- K1b: W_proj fp32 -> bf16
__global__ __launch_bounds__(256) void k_cvt(const float* __restrict__ W, u16* __restrict__ Wb) {
    const int i = (blockIdx.x * 256 + threadIdx.x) * 4;   // 2048 blocks covers 2048*1024
    float4 v = *(const float4*)(W + i);
    ushort4 o = {f2bf(v.x), f2bf(v.y), f2bf(v.z), f2bf(v.w)};
    *(ushort4*)(Wb + i) = o;
}

// ---------------------------------------------------------------- K2: 256x256 8-wave 4-phase bf16 GEMM
// A [T,1024] bf16 (tokens), B=W_proj [2048,1024] bf16.  BM=BN=256, BK=64, 8 waves (2M x 4N),
// per-wave output 128(tok) x 64(inner).  Double-buffered 128 KiB LDS, counted vmcnt (never 0
// in main loop), raw s_barrier pairs per phase, setprio(1) around each 16-MFMA cluster.
// Swapped MFMA operands (wf as A) -> acc holds C^T: lane (q,c15) reg r = (inner=q*4+r, token=c15).
// Fused epilogue: silu + W_state^T projection via 16x16x16 MFMA -> partials[T][32][8],
// slot = bn*4 + (w&3).
#define STAGE_A(i, kb, buf) \
    __builtin_amdgcn_global_load_lds( \
        (const __attribute__((address_space(1))) void*)(Ag + (i) * 65536 + (kb) * 64), \
        (__attribute__((address_space(3))) void*)(lA + (buf) * 32768 + (i) * 4096), 16, 0, 0)
#define STAGE_B(i, kb, buf) \
    __builtin_amdgcn_global_load_lds( \
        (const __attribute__((address_space(1))) void*)(Bg + (i) * 65536 + (kb) * 64), \
        (__attribute__((address_space(3))) void*)(lB + (buf) * 32768 + (i) * 4096), 16, 0, 0)
#define FENCE() asm volatile("" ::: "memory")
#define BARRIER() do { FENCE(); __builtin_amdgcn_s_barrier(); FENCE(); } while (0)

__global__ __launch_bounds__(512, 2) void k_gemm(const u16* __restrict__ A,
                                                 const u16* __restrict__ B,
                                                 const float* __restrict__ bproj,
                                                 const float* __restrict__ Wstate,   // [8][2048] fp32
                                                 float* __restrict__ part) {
    __shared__ u16 sm[65536];   // 128 KiB: [buf0: A 32K | B 32K][buf1: A 32K | B 32K]
    const int t = threadIdx.x;
    const int w = t >> 6, lane = t & 63;
    const int q = lane >> 4, c15 = lane & 15;
    const int bn = blockIdx.x, bm = blockIdx.y;
    const int wm = (w >> 2) * 128, wn = (w & 3) * 64;

    f32x4 acc[4][8];   // [ci = inner tile 0..3][ti = token tile 0..7]
#pragma unroll
    for (int ci = 0; ci < 4; ++ci)
#pragma unroll
        for (int ti = 0; ti < 8; ++ti) acc[ci][ti] = (f32x4){0.f, 0.f, 0.f, 0.f};

    // staging coords: 512 thr * 16B = 64 rows/issue; XOR chunk swizzle (involution, rule 21)
    const int srow = t >> 3;                       // 0..63
    const int gch = (t & 7) ^ (srow & 7);
    const u16* Ag = A + (size_t)(bm * 256 + srow) * 1024 + gch * 8;
    const u16* Bg = B + (size_t)(bn * 256 + srow) * 1024 + gch * 8;
    u16* lA = &sm[t * 8];
    u16* lB = &sm[16384 + t * 8];

    // LDS fragment reads (swizzled chunk; row&7 == c15&7 since wm/wn/ti*16 are 8-multiples)
    auto LDA = [&](int buf, int ti, int ks) -> bf16x8 {
        const int row = wm + ti * 16 + c15;
        const int ch = (ks * 4 + q) ^ (c15 & 7);
        return *(const bf16x8*)&sm[buf * 32768 + row * 64 + ch * 8];
    };
    auto LDB = [&](int buf, int ci, int ks) -> bf16x8 {
        const int row = wn + ci * 16 + c15;
        const int ch = (ks * 4 + q) ^ (c15 & 7);
        return *(const bf16x8*)&sm[buf * 32768 + 16384 + row * 64 + ch * 8];
    };

    // ---- prologue: tile0 fully staged into buf0, tile1 slots{0,1} in flight into buf1
    STAGE_A(0, 0, 0); STAGE_A(1, 0, 0); STAGE_A(2, 0, 0); STAGE_A(3, 0, 0);
    STAGE_B(0, 0, 0); STAGE_B(1, 0, 0); STAGE_B(2, 0, 0); STAGE_B(3, 0, 0);
    STAGE_A(0, 1, 1); STAGE_A(1, 1, 1);
    asm volatile("s_waitcnt vmcnt(2)" ::: "memory");
    BARRIER();

#pragma unroll 2
    for (int tt = 0; tt < 16; ++tt) {
        const int cur = tt & 1, nxt = cur ^ 1;
        const int kb1 = (tt + 1) & 15, kb2 = (tt + 2) & 15;   // wrap: stages past K are harmless
        bf16x8 xf[4][2], wf[4][2];
        // ---------------- P1: tokens half0 + inner half0
#pragma unroll
        for (int ti = 0; ti < 4; ++ti)
#pragma unroll
            for (int ks = 0; ks < 2; ++ks) xf[ti][ks] = LDA(cur, ti, ks);
#pragma unroll
        for (int ci = 0; ci < 2; ++ci)
#pragma unroll
            for (int ks = 0; ks < 2; ++ks) wf[ci][ks] = LDB(cur, ci, ks);
        STAGE_A(2, kb1, nxt); STAGE_A(3, kb1, nxt);
        BARRIER();
        __builtin_amdgcn_s_setprio(1);
#pragma unroll
        for (int ci = 0; ci < 2; ++ci)
#pragma unroll
            for (int ti = 0; ti < 4; ++ti)
#pragma unroll
                for (int ks = 0; ks < 2; ++ks)
                    acc[ci][ti] = __builtin_amdgcn_mfma_f32_16x16x32_bf16(wf[ci][ks], xf[ti][ks], acc[ci][ti], 0, 0, 0);
        __builtin_amdgcn_s_setprio(0);
        BARRIER();
        // ---------------- P2: tokens half0 + inner half1
#pragma unroll
        for (int ci = 2; ci < 4; ++ci)
#pragma unroll
            for (int ks = 0; ks < 2; ++ks) wf[ci][ks] = LDB(cur, ci, ks);
        STAGE_B(0, kb1, nxt); STAGE_B(1, kb1, nxt);
        BARRIER();
        __builtin_amdgcn_s_setprio(1);
#pragma unroll
        for (int ci = 2; ci < 4; ++ci)
#pragma unroll
            for (int ti = 0; ti < 4; ++ti)
#pragma unroll
                for (int ks = 0; ks < 2; ++ks)
                    acc[ci][ti] = __builtin_amdgcn_mfma_f32_16x16x32_bf16(wf[ci][ks], xf[ti][ks], acc[ci][ti], 0, 0, 0);
        __builtin_amdgcn_s_setprio(0);
        BARRIER();
        // ---------------- P3: tokens half1 + inner half0
#pragma unroll
        for (int ti = 0; ti < 4; ++ti)
#pragma unroll
            for (int ks = 0; ks < 2; ++ks) xf[ti][ks] = LDA(cur, 4 + ti, ks);
        STAGE_B(2, kb1, nxt); STAGE_B(3, kb1, nxt);
        BARRIER();
        __builtin_amdgcn_s_setprio(1);
#pragma unroll
        for (int ci = 0; ci < 2; ++ci)
#pragma unroll
            for (int ti = 0; ti < 4; ++ti)
#pragma unroll
                for (int ks = 0; ks < 2; ++ks)
                    acc[ci][4 + ti] = __builtin_amdgcn_mfma_f32_16x16x32_bf16(wf[ci][ks], xf[ti][ks], acc[ci][4 + ti], 0, 0, 0);
        __builtin_amdgcn_s_setprio(0);
        BARRIER();
        // ---------------- P4: tokens half1 + inner half1; stage tile tt+2 A{0,1} into buf[cur]
        // (all reads of buf[cur] finished at P3's end barrier); counted vmcnt: 10 outstanding
        // -> drain 8 = all of tile tt+1, keep tile tt+2's 2 in flight.
        STAGE_A(0, kb2, cur); STAGE_A(1, kb2, cur);
        asm volatile("s_waitcnt vmcnt(2)" ::: "memory");
        BARRIER();
        __builtin_amdgcn_s_setprio(1);
#pragma unroll
        for (int ci = 2; ci < 4; ++ci)
#pragma unroll
            for (int ti = 0; ti < 4; ++ti)
#pragma unroll
                for (int ks = 0; ks < 2; ++ks)
                    acc[ci][4 + ti] = __builtin_amdgcn_mfma_f32_16x16x32_bf16(wf[ci][ks], xf[ti][ks], acc[ci][4 + ti], 0, 0, 0);
        __builtin_amdgcn_s_setprio(0);
        BARRIER();
    }

    // ---- fused epilogue: sv = silu(acc + b_proj) (bf16), partials via 16x16x16 MFMA.
    // Lane (q,c15) holds acc[ci][ti][r] at (inner = bn*256+wn+ci*16+q*4+r, token = bm*256+wm+ti*16+c15).
    const int ib0 = bn * 256 + wn + q * 4;
    f32x4 bp4[4];
    bf16x4 wsf[4];
#pragma unroll
    for (int ci = 0; ci < 4; ++ci) {
        const int ib = ib0 + ci * 16;
        bp4[ci] = *(const f32x4*)(bproj + ib);
        if (c15 < 8) {
            f32x4 wv = *(const f32x4*)(Wstate + (size_t)c15 * D_INNER + ib);
            wsf[ci] = (bf16x4){(short)f2bf(wv[0]), (short)f2bf(wv[1]), (short)f2bf(wv[2]), (short)f2bf(wv[3])};
        } else {
            wsf[ci] = (bf16x4){0, 0, 0, 0};   // A-frag rows 8..15 = 0 -> D rows 8..15 = 0 (unused)
        }
    }
    const int slot = bn * 4 + (w & 3);
#pragma unroll
    for (int ti = 0; ti < 8; ++ti) {
        f32x4 a2 = (f32x4){0.f, 0.f, 0.f, 0.f};
#pragma unroll
        for (int ci = 0; ci < 4; ++ci) {
            bf16x4 sv;
#pragma unroll
            for (int r = 0; r < 4; ++r) {
                const float s = silu(acc[ci][ti][r] + bp4[ci][r]);
                sv[r] = (short)f2bf(s);
            }
            a2 = mfma_16x16x16_bf16(wsf[ci], sv, a2);
        }
        if (q < 2) {   // q=0: states 0..3, q=1: states 4..7 -> one contiguous 16B store
            const int row = bm * 256 + wm + ti * 16 + c15;
            *(f32x4*)(part + (size_t)row * 256 + slot * 8 + q * 4) = a2;
        }
    }
}

// ---------------------------------------------------------------- K3: sum partials, silu, xW_out^T, +x
// v2: W_out transposed in LDS (wT[n][d], contiguous conflict-free float4 reads);
// x / bout / out all 16B-per-lane float4 (G13).
__global__ __launch_bounds__(256) void k_out2(const float* __restrict__ x,
                                              const float* __restrict__ part,   // [T][32][8]
                                              const float* __restrict__ Wout,   // [1024][8]
                                              const float* __restrict__ bout,   // [1024]
                                              const float* __restrict__ bstate, // [8]
                                              const float* __restrict__ s0,     // [8]
                                              float* __restrict__ out) {
    __shared__ float wT[8][1024];   // 32 KB, transposed: wT[n][d] = Wout[d][n]
    const int t = threadIdx.x;
    const float4* Wg4 = (const float4*)Wout;   // 2048 float4; g -> (d = g>>1, h = (g&1)*4)
#pragma unroll
    for (int i = 0; i < 8; ++i) {
        const int g = i * 256 + t;
        const int d = g >> 1, h = (g & 1) * 4;
        float4 v = Wg4[g];
        wT[h + 0][d] = v.x;
        wT[h + 1][d] = v.y;
        wT[h + 2][d] = v.z;
        wT[h + 3][d] = v.w;
    }
    __syncthreads();

    const int w = t >> 6, lane = t & 63;
    const int tok = blockIdx.x * 4 + w;

    // partials: 256 f32 per token = 64 float4, one per lane; butterfly-reduce (parity-preserving)
    const float4* p4 = (const float4*)(part + (size_t)tok * 256);
    float4 pv = p4[lane];
    float pa[4] = {pv.x, pv.y, pv.z, pv.w};
#pragma unroll
    for (int off = 2; off < 64; off <<= 1)
#pragma unroll
        for (int j = 0; j < 4; ++j) pa[j] += __shfl_xor(pa[j], off, 64);
    float cs[8];
#pragma unroll
    for (int j = 0; j < 4; ++j) {
        const float sl = __shfl(pa[j], 0, 64);          // states 0..3 on even lanes
        const float sh = __shfl(pa[j], 1, 64);          // states 4..7 on odd lanes
        cs[j]     = silu(sl + s0[j]     + bstate[j]);
        cs[4 + j] = silu(sh + s0[4 + j] + bstate[4 + j]);
    }

    const float4* xr4 = (const float4*)(x + (size_t)tok * D_MODEL);
    const float4* bo4 = (const float4*)bout;
    float4* o4 = (float4*)(out + (size_t)tok * D_MODEL);
#pragma unroll
    for (int c = 0; c < 4; ++c) {
        const int dv = c * 64 + lane;          // float4 index; d = dv*4
        const int d = dv * 4;
        float4 xv = xr4[dv];
        float4 bv = bo4[dv];
        float4 r;
        r.x = xv.x + bv.x; r.y = xv.y + bv.y; r.z = xv.z + bv.z; r.w = xv.w + bv.w;
#pragma unroll
        for (int n = 0; n < 8; ++n) {
            const float4 wn = *(const float4*)&wT[n][d];
            r.x += cs[n] * wn.x;
            r.y += cs[n] * wn.y;
            r.z += cs[n] * wn.z;
            r.w += cs[n] * wn.w;
        }
        o4[dv] = r;
    }
}

extern "C" void kernel_launch(void* const* d_in, const int* in_sizes, int n_in,
                              void* d_out, int out_size, void* d_ws, size_t ws_size,
                              hipStream_t stream) {
    const float* x      = (const float*)d_in[0];
    const float* Wproj  = (const float*)d_in[1];
    const float* bproj  = (const float*)d_in[2];
    const float* Wstate = (const float*)d_in[3];
    const float* bstate = (const float*)d_in[4];
    const float* Wout   = (const float*)d_in[5];
    const float* bout   = (const float*)d_in[6];
    const float* s0     = (const float*)d_in[7];
    const float* gamma  = (const float*)d_in[8];
    const float* beta   = (const float*)d_in[9];

    u16* xn = (u16*)d_out;                               // LN output (bf16) borrows d_out;
                                                         // fully consumed by k_gemm before k_out2 overwrites
    u16* Wb = (u16*)d_ws;                                // 4 MB
    float* partials = (float*)((char*)d_ws + (size_t)D_INNER * D_MODEL * sizeof(u16));  // 51.4 MB
    float* out = (float*)d_out;

    k_ln  <<<T_TOKENS / 4, 256, 0, stream>>>(x, gamma, beta, xn);
    k_cvt <<<(D_INNER * D_MODEL) / 1024, 256, 0, stream>>>(Wproj, Wb);
    k_gemm<<<dim3(D_INNER / 256, T_TOKENS / 256), 512, 0, stream>>>(xn, Wb, bproj, Wstate, partials);
    k_out2<<<T_TOKENS / 4, 256, 0, stream>>>(x, partials, Wout, bout, bstate, s0, out);
}

// Round 4
// 654.956 us; speedup vs baseline: 1.3298x; 1.0384x over previous
//
#include <hip/hip_runtime.h>
#include <hip/hip_bf16.h>

typedef unsigned short u16;
typedef unsigned int u32;
typedef __attribute__((ext_vector_type(8))) short bf16x8;   // 8 bf16 in 4 VGPRs
typedef __attribute__((ext_vector_type(4))) short bf16x4;   // 4 bf16 in 2 VGPRs
typedef __attribute__((ext_vector_type(8))) u16 u16x8;      // 16B store unit
typedef __attribute__((ext_vector_type(4))) float f32x4;

#define T_TOKENS 50176   // 2*128*196
#define D_MODEL  1024
#define D_INNER  2048
#define D_STATE  8

__device__ __forceinline__ u16 f2bf(float f) {
    u32 u = __builtin_bit_cast(u32, f);
    u += 0x7fffu + ((u >> 16) & 1u);   // RNE
    return (u16)(u >> 16);
}
__device__ __forceinline__ float silu(float v) {
    return v / (1.f + __expf(-v));
}

// K=16 bf16 MFMA for the fused state-projection epilogue.
__device__ __forceinline__ f32x4 mfma_16x16x16_bf16(bf16x4 a, bf16x4 b, f32x4 c) {
#if __has_builtin(__builtin_amdgcn_mfma_f32_16x16x16bf16_1k)
    return __builtin_amdgcn_mfma_f32_16x16x16bf16_1k(a, b, c, 0, 0, 0);
#else
    f32x4 d;
    asm("v_mfma_f32_16x16x16_bf16 %0, %1, %2, %3" : "=v"(d) : "v"(a), "v"(b), "v"(c));
    return d;
#endif
}

// ---------------------------------------------------------------- K1: LayerNorm -> bf16 + W_proj cvt (merged)
// blocks [0,12544): LN (4 waves, 1 token each).  blocks [12544,14592): W_proj fp32->bf16.
__global__ __launch_bounds__(256) void k_ln(const float* __restrict__ x,
                                            const float* __restrict__ gamma,
                                            const float* __restrict__ beta,
                                            u16* __restrict__ xn,
                                            const float* __restrict__ W,
                                            u16* __restrict__ Wb) {
    const int bid = blockIdx.x;
    if (bid >= 12544) {   // ---- cvt branch: 2048 blocks cover 2048*1024 elements
        const int i = ((bid - 12544) * 256 + threadIdx.x) * 4;
        float4 v = *(const float4*)(W + i);
        ushort4 o = {f2bf(v.x), f2bf(v.y), f2bf(v.z), f2bf(v.w)};
        *(ushort4*)(Wb + i) = o;
        return;
    }
    const int w = threadIdx.x >> 6, lane = threadIdx.x & 63;
    const int tok = bid * 4 + w;                        // 12544 blocks * 4 waves = 50176
    const float* xr = x + (size_t)tok * D_MODEL;
    float4 v[2][2];
    float s1 = 0.f, s2 = 0.f;
#pragma unroll
    for (int c = 0; c < 2; ++c) {
        const int d = c * 512 + lane * 8;
        v[c][0] = *(const float4*)(xr + d);
        v[c][1] = *(const float4*)(xr + d + 4);
#pragma unroll
        for (int p = 0; p < 2; ++p) {
            s1 += v[c][p].x + v[c][p].y + v[c][p].z + v[c][p].w;
            s2 += v[c][p].x * v[c][p].x + v[c][p].y * v[c][p].y
                + v[c][p].z * v[c][p].z + v[c][p].w * v[c][p].w;
        }
    }
#pragma unroll
    for (int off = 32; off; off >>= 1) {
        s1 += __shfl_xor(s1, off, 64);
        s2 += __shfl_xor(s2, off, 64);
    }
    const float mu = s1 * (1.f / 1024.f);
    const float var = s2 * (1.f / 1024.f) - mu * mu;
    const float rstd = rsqrtf(var + 1e-5f);
    u16* orow = xn + (size_t)tok * D_MODEL;
#pragma unroll
    for (int c = 0; c < 2; ++c) {
        const int d = c * 512 + lane * 8;
        float4 g0 = *(const float4*)(gamma + d);
        float4 g1 = *(const float4*)(gamma + d + 4);
        float4 b0 = *(const float4*)(beta + d);
        float4 b1 = *(const float4*)(beta + d + 4);
        u16x8 o;
        o[0] = f2bf((v[c][0].x - mu) * rstd * g0.x + b0.x);
        o[1] = f2bf((v[c][0].y - mu) * rstd * g0.y + b0.y);
        o[2] = f2bf((v[c][0].z - mu) * rstd * g0.z + b0.z);
        o[3] = f2bf((v[c][0].w - mu) * rstd * g0.w + b0.w);
        o[4] = f2bf((v[c][1].x - mu) * rstd * g1.x + b1.x);
        o[5] = f2bf((v[c][1].y - mu) * rstd * g1.y + b1.y);
        o[6] = f2bf((v[c][1].z - mu) * rstd * g1.z + b1.z);
        o[7] = f2bf((v[c][1].w - mu) * rstd * g1.w + b1.w);
        *(u16x8*)(orow + d) = o;
    }
}

// ---------------------------------------------------------------- K2: 256x256 8-wave 4-phase bf16 GEMM
// A [T,1024] bf16 (tokens), B=W_proj [2048,1024] bf16.  BM=BN=256, BK=64, 8 waves (2M x 4N),
// per-wave output 128(tok) x 64(inner).  Double-buffered 128 KiB LDS, counted vmcnt (never 0
// in main loop), raw s_barrier pairs per phase, setprio(1) around each 16-MFMA cluster.
// Swapped MFMA operands (wf as A) -> acc holds C^T: lane (q,c15) reg r = (inner=q*4+r, token=c15).
// Fused epilogue: silu + W_state^T projection via 16x16x16 MFMA, then IN-BLOCK LDS reduction
// across the 4 n-waves (they share token rows) -> partials[T][8][8] fp32, slot = bn.
// XCD swizzle: bm = lin%196, bn = lin/196 so a bm's 8 bn-siblings share ~2 XCD L2s (A-tile reuse).
#define STAGE_A(i, kb, buf) \
    __builtin_amdgcn_global_load_lds( \
        (const __attribute__((address_space(1))) void*)(Ag + (i) * 65536 + (kb) * 64), \
        (__attribute__((address_space(3))) void*)(lA + (buf) * 32768 + (i) * 4096), 16, 0, 0)
#define STAGE_B(i, kb, buf) \
    __builtin_amdgcn_global_load_lds( \
        (const __attribute__((address_space(1))) void*)(Bg + (i) * 65536 + (kb) * 64), \
        (__attribute__((address_space(3))) void*)(lB + (buf) * 32768 + (i) * 4096), 16, 0, 0)
#define FENCE() asm volatile("" ::: "memory")
#define BARRIER() do { FENCE(); __builtin_amdgcn_s_barrier(); FENCE(); } while (0)

__global__ __launch_bounds__(512, 2) void k_gemm(const u16* __restrict__ A,
                                                 const u16* __restrict__ B,
                                                 const float* __restrict__ bproj,
                                                 const float* __restrict__ Wstate,   // [8][2048] fp32
                                                 float* __restrict__ part) {
    __shared__ u16 sm[65536];   // 128 KiB: [buf0: A 32K | B 32K][buf1: A 32K | B 32K]
    const int t = threadIdx.x;
    const int w = t >> 6, lane = t & 63;
    const int q = lane >> 4, c15 = lane & 15;
    const int lin = blockIdx.y * 8 + blockIdx.x;        // 0..1567
    const int bm = lin % 196, bn = lin / 196;           // bijective XCD-locality remap
    const int wm = (w >> 2) * 128, wn = (w & 3) * 64;

    f32x4 acc[4][8];   // [ci = inner tile 0..3][ti = token tile 0..7]
#pragma unroll
    for (int ci = 0; ci < 4; ++ci)
#pragma unroll
        for (int ti = 0; ti < 8; ++ti) acc[ci][ti] = (f32x4){0.f, 0.f, 0.f, 0.f};

    // staging coords: 512 thr * 16B = 64 rows/issue; XOR chunk swizzle (involution, rule 21)
    const int srow = t >> 3;                       // 0..63
    const int gch = (t & 7) ^ (srow & 7);
    const u16* Ag = A + (size_t)(bm * 256 + srow) * 1024 + gch * 8;
    const u16* Bg = B + (size_t)(bn * 256 + srow) * 1024 + gch * 8;
    u16* lA = &sm[t * 8];
    u16* lB = &sm[16384 + t * 8];

    // LDS fragment reads (swizzled chunk; row&7 == c15&7 since wm/wn/ti*16 are 8-multiples)
    auto LDA = [&](int buf, int ti, int ks) -> bf16x8 {
        const int row = wm + ti * 16 + c15;
        const int ch = (ks * 4 + q) ^ (c15 & 7);
        return *(const bf16x8*)&sm[buf * 32768 + row * 64 + ch * 8];
    };
    auto LDB = [&](int buf, int ci, int ks) -> bf16x8 {
        const int row = wn + ci * 16 + c15;
        const int ch = (ks * 4 + q) ^ (c15 & 7);
        return *(const bf16x8*)&sm[buf * 32768 + 16384 + row * 64 + ch * 8];
    };

    // ---- prologue: tile0 fully staged into buf0, tile1 slots{0,1} in flight into buf1
    STAGE_A(0, 0, 0); STAGE_A(1, 0, 0); STAGE_A(2, 0, 0); STAGE_A(3, 0, 0);
    STAGE_B(0, 0, 0); STAGE_B(1, 0, 0); STAGE_B(2, 0, 0); STAGE_B(3, 0, 0);
    STAGE_A(0, 1, 1); STAGE_A(1, 1, 1);
    asm volatile("s_waitcnt vmcnt(2)" ::: "memory");
    BARRIER();

#pragma unroll 2
    for (int tt = 0; tt < 16; ++tt) {
        const int cur = tt & 1, nxt = cur ^ 1;
        const int kb1 = (tt + 1) & 15, kb2 = (tt + 2) & 15;   // wrap: stages past K are harmless
        bf16x8 xf[4][2], wf[4][2];
        // ---------------- P1: tokens half0 + inner half0
#pragma unroll
        for (int ti = 0; ti < 4; ++ti)
#pragma unroll
            for (int ks = 0; ks < 2; ++ks) xf[ti][ks] = LDA(cur, ti, ks);
#pragma unroll
        for (int ci = 0; ci < 2; ++ci)
#pragma unroll
            for (int ks = 0; ks < 2; ++ks) wf[ci][ks] = LDB(cur, ci, ks);
        STAGE_A(2, kb1, nxt); STAGE_A(3, kb1, nxt);
        BARRIER();
        __builtin_amdgcn_s_setprio(1);
#pragma unroll
        for (int ci = 0; ci < 2; ++ci)
#pragma unroll
            for (int ti = 0; ti < 4; ++ti)
#pragma unroll
                for (int ks = 0; ks < 2; ++ks)
                    acc[ci][ti] = __builtin_amdgcn_mfma_f32_16x16x32_bf16(wf[ci][ks], xf[ti][ks], acc[ci][ti], 0, 0, 0);
        __builtin_amdgcn_s_setprio(0);
        BARRIER();
        // ---------------- P2: tokens half0 + inner half1
#pragma unroll
        for (int ci = 2; ci < 4; ++ci)
#pragma unroll
            for (int ks = 0; ks < 2; ++ks) wf[ci][ks] = LDB(cur, ci, ks);
        STAGE_B(0, kb1, nxt); STAGE_B(1, kb1, nxt);
        BARRIER();
        __builtin_amdgcn_s_setprio(1);
#pragma unroll
        for (int ci = 2; ci < 4; ++ci)
#pragma unroll
            for (int ti = 0; ti < 4; ++ti)
#pragma unroll
                for (int ks = 0; ks < 2; ++ks)
                    acc[ci][ti] = __builtin_amdgcn_mfma_f32_16x16x32_bf16(wf[ci][ks], xf[ti][ks], acc[ci][ti], 0, 0, 0);
        __builtin_amdgcn_s_setprio(0);
        BARRIER();
        // ---------------- P3: tokens half1 + inner half0
#pragma unroll
        for (int ti = 0; ti < 4; ++ti)
#pragma unroll
            for (int ks = 0; ks < 2; ++ks) xf[ti][ks] = LDA(cur, 4 + ti, ks);
        STAGE_B(2, kb1, nxt); STAGE_B(3, kb1, nxt);
        BARRIER();
        __builtin_amdgcn_s_setprio(1);
#pragma unroll
        for (int ci = 0; ci < 2; ++ci)
#pragma unroll
            for (int ti = 0; ti < 4; ++ti)
#pragma unroll
                for (int ks = 0; ks < 2; ++ks)
                    acc[ci][4 + ti] = __builtin_amdgcn_mfma_f32_16x16x32_bf16(wf[ci][ks], xf[ti][ks], acc[ci][4 + ti], 0, 0, 0);
        __builtin_amdgcn_s_setprio(0);
        BARRIER();
        // ---------------- P4: tokens half1 + inner half1; stage tile tt+2 A{0,1} into buf[cur]
        // (all reads of buf[cur] finished at P3's end barrier); counted vmcnt: 10 outstanding
        // -> drain 8 = all of tile tt+1, keep tile tt+2's 2 in flight.
        STAGE_A(0, kb2, cur); STAGE_A(1, kb2, cur);
        asm volatile("s_waitcnt vmcnt(2)" ::: "memory");
        BARRIER();
        __builtin_amdgcn_s_setprio(1);
#pragma unroll
        for (int ci = 2; ci < 4; ++ci)
#pragma unroll
            for (int ti = 0; ti < 4; ++ti)
#pragma unroll
                for (int ks = 0; ks < 2; ++ks)
                    acc[ci][4 + ti] = __builtin_amdgcn_mfma_f32_16x16x32_bf16(wf[ci][ks], xf[ti][ks], acc[ci][4 + ti], 0, 0, 0);
        __builtin_amdgcn_s_setprio(0);
        BARRIER();
    }

    // ---- drain in-flight stages, then sm is reusable as scratch
    asm volatile("s_waitcnt vmcnt(0)" ::: "memory");
    BARRIER();

    // ---- fused epilogue: sv = silu(acc + b_proj) (bf16), per-wave 8-state projection via
    // 16x16x16 MFMA, then cross-n-wave LDS reduction -> part[T][8][8], slot = bn.
    // Lane (q,c15) holds acc[ci][ti][r] at (inner = bn*256+wn+ci*16+q*4+r, token = bm*256+wm+ti*16+c15).
    const int ib0 = bn * 256 + wn + q * 4;
    f32x4 bp4[4];
    bf16x4 wsf[4];
#pragma unroll
    for (int ci = 0; ci < 4; ++ci) {
        const int ib = ib0 + ci * 16;
        bp4[ci] = *(const f32x4*)(bproj + ib);
        if (c15 < 8) {
            f32x4 wv = *(const f32x4*)(Wstate + (size_t)c15 * D_INNER + ib);
            wsf[ci] = (bf16x4){(short)f2bf(wv[0]), (short)f2bf(wv[1]), (short)f2bf(wv[2]), (short)f2bf(wv[3])};
        } else {
            wsf[ci] = (bf16x4){0, 0, 0, 0};   // A-frag rows 8..15 = 0 -> D rows 8..15 = 0 (unused)
        }
    }
    float* smf = (float*)sm;            // scratch [4 n-waves][256 tokens][8 states] = 32 KB
    const int wq = w & 3;
#pragma unroll
    for (int ti = 0; ti < 8; ++ti) {
        f32x4 a2 = (f32x4){0.f, 0.f, 0.f, 0.f};
#pragma unroll
        for (int ci = 0; ci < 4; ++ci) {
            bf16x4 sv;
#pragma unroll
            for (int r = 0; r < 4; ++r) {
                const float s = silu(acc[ci][ti][r] + bp4[ci][r]);
                sv[r] = (short)f2bf(s);
            }
            a2 = mfma_16x16x16_bf16(wsf[ci], sv, a2);
        }
        if (q < 2) {   // q=0: states 0..3, q=1: states 4..7
            const int tl = wm + ti * 16 + c15;                   // 0..255
            *(f32x4*)&smf[(wq * 256 + tl) * 8 + q * 4] = a2;
        }
    }
    __syncthreads();
    {
        // 512 threads cover 256 tokens x 8 states: thread -> (token = t>>1, 4 states)
        const int tl = t >> 1, s4 = (t & 1) * 4;
        f32x4 s = (f32x4){0.f, 0.f, 0.f, 0.f};
#pragma unroll
        for (int sl = 0; sl < 4; ++sl) {
            f32x4 v = *(const f32x4*)&smf[(sl * 256 + tl) * 8 + s4];
            s[0] += v[0]; s[1] += v[1]; s[2] += v[2]; s[3] += v[3];
        }
        *(f32x4*)(part + (size_t)(bm * 256 + tl) * 64 + bn * 8 + s4) = s;
    }
}

// ---------------------------------------------------------------- K3: sum partials, silu, xW_out^T, +x
// part is now [T][8 slots][8 states] (12.8 MB).  One wave per token: lane = slot*8+state,
// 3 xor-shfl steps sum the slots; then float4 main loop (x/bout/out 16B per lane).
__global__ __launch_bounds__(256) void k_out2(const float* __restrict__ x,
                                              const float* __restrict__ part,   // [T][8][8]
                                              const float* __restrict__ Wout,   // [1024][8]
                                              const float* __restrict__ bout,   // [1024]
                                              const float* __restrict__ bstate, // [8]
                                              const float* __restrict__ s0,     // [8]
                                              float* __restrict__ out) {
    __shared__ float wT[8][1024];   // 32 KB, transposed: wT[n][d] = Wout[d][n]
    const int t = threadIdx.x;
    const float4* Wg4 = (const float4*)Wout;   // 2048 float4; g -> (d = g>>1, h = (g&1)*4)
#pragma unroll
    for (int i = 0; i < 8; ++i) {
        const int g = i * 256 + t;
        const int d = g >> 1, h = (g & 1) * 4;
        float4 v = Wg4[g];
        wT[h + 0][d] = v.x;
        wT[h + 1][d] = v.y;
        wT[h + 2][d] = v.z;
        wT[h + 3][d] = v.w;
    }
    __syncthreads();

    const int w = t >> 6, lane = t & 63;
    const int tok = blockIdx.x * 4 + w;

    // lane = slot*8 + state; reduce over slots (bits 3..5)
    float v = part[(size_t)tok * 64 + lane];
#pragma unroll
    for (int off = 8; off < 64; off <<= 1) v += __shfl_xor(v, off, 64);
    const int st = lane & 7;
    const float vv = silu(v + s0[st] + bstate[st]);
    float cs[8];
#pragma unroll
    for (int j = 0; j < 8; ++j) cs[j] = __shfl(vv, j, 64);

    const float4* xr4 = (const float4*)(x + (size_t)tok * D_MODEL);
    const float4* bo4 = (const float4*)bout;
    float4* o4 = (float4*)(out + (size_t)tok * D_MODEL);
#pragma unroll
    for (int c = 0; c < 4; ++c) {
        const int dv = c * 64 + lane;          // float4 index; d = dv*4
        const int d = dv * 4;
        float4 xv = xr4[dv];
        float4 bv = bo4[dv];
        float4 r;
        r.x = xv.x + bv.x; r.y = xv.y + bv.y; r.z = xv.z + bv.z; r.w = xv.w + bv.w;
#pragma unroll
        for (int n = 0; n < 8; ++n) {
            const float4 wn = *(const float4*)&wT[n][d];
            r.x += cs[n] * wn.x;
            r.y += cs[n] * wn.y;
            r.z += cs[n] * wn.z;
            r.w += cs[n] * wn.w;
        }
        o4[dv] = r;
    }
}

extern "C" void kernel_launch(void* const* d_in, const int* in_sizes, int n_in,
                              void* d_out, int out_size, void* d_ws, size_t ws_size,
                              hipStream_t stream) {
    const float* x      = (const float*)d_in[0];
    const float* Wproj  = (const float*)d_in[1];
    const float* bproj  = (const float*)d_in[2];
    const float* Wstate = (const float*)d_in[3];
    const float* bstate = (const float*)d_in[4];
    const float* Wout   = (const float*)d_in[5];
    const float* bout   = (const float*)d_in[6];
    const float* s0     = (const float*)d_in[7];
    const float* gamma  = (const float*)d_in[8];
    const float* beta   = (const float*)d_in[9];

    u16* xn = (u16*)d_out;                               // LN output (bf16) borrows d_out;
                                                         // fully consumed by k_gemm before k_out2 overwrites
    u16* Wb = (u16*)d_ws;                                // 4 MB
    float* partials = (float*)((char*)d_ws + (size_t)D_INNER * D_MODEL * sizeof(u16));  // 12.8 MB
    float* out = (float*)d_out;

    k_ln  <<<12544 + 2048, 256, 0, stream>>>(x, gamma, beta, xn, Wproj, Wb);
    k_gemm<<<dim3(8, 196), 512, 0, stream>>>(xn, Wb, bproj, Wstate, partials);
    k_out2<<<T_TOKENS / 4, 256, 0, stream>>>(x, partials, Wout, bout, bstate, s0, out);
}